// Round 6
// baseline (558.392 us; speedup 1.0000x reference)
//
#include <hip/hip_runtime.h>
#include <hip/hip_bf16.h>

#define T_TOK 2048
#define DIMS  1024
#define HID   4096
#define NE    8

typedef __bf16 bf16x8 __attribute__((ext_vector_type(8)));
typedef float  f32x4  __attribute__((ext_vector_type(4)));

__device__ __forceinline__ unsigned short f2bf(float f) {
  unsigned u = __float_as_uint(f);
  u += 0x7FFFu + ((u >> 16) & 1u);
  return (unsigned short)(u >> 16);
}
__device__ __forceinline__ float bf2f(unsigned short s) {
  return __uint_as_float(((unsigned)s) << 16);
}

__device__ __forceinline__ void g2l16(const void* g, void* l) {
  __builtin_amdgcn_global_load_lds((const __attribute__((address_space(1))) void*)g,
                                   (__attribute__((address_space(3))) void*)l,
                                   16, 0, 0);
}

// ---------------- routing (+ fused u->bf16 cast) ----------------
__global__ __launch_bounds__(256) void k_route(const float* __restrict__ u,
    const float* __restrict__ cent, const float* __restrict__ sbias,
    int* __restrict__ topk_idx, float* __restrict__ topk_val,
    unsigned short* __restrict__ ub) {
  int wave = threadIdx.x >> 6;
  int lane = threadIdx.x & 63;
  int t = blockIdx.x * 4 + wave;
  const float* ur = u + (size_t)t * DIMS;
  float p[NE];
#pragma unroll
  for (int n = 0; n < NE; n++) p[n] = 0.f;
#pragma unroll
  for (int ch = 0; ch < 4; ch++) {
    int d = ch * 256 + lane * 4;
    float4 uv = *(const float4*)(ur + d);
    ushort4 o4;
    o4.x = f2bf(uv.x); o4.y = f2bf(uv.y); o4.z = f2bf(uv.z); o4.w = f2bf(uv.w);
    *(ushort4*)(ub + (size_t)t * DIMS + d) = o4;
#pragma unroll
    for (int n = 0; n < NE; n++) {
      float4 cv = *(const float4*)(cent + n * DIMS + d);
      p[n] += uv.x * cv.x + uv.y * cv.y + uv.z * cv.z + uv.w * cv.w;
    }
  }
#pragma unroll
  for (int n = 0; n < NE; n++) {
#pragma unroll
    for (int o = 32; o > 0; o >>= 1) p[n] += __shfl_xor(p[n], o);
  }
  if (lane == 0) {
    float g[NE];
    float m = -1e30f;
#pragma unroll
    for (int n = 0; n < NE; n++) { g[n] = p[n] + sbias[n]; m = fmaxf(m, g[n]); }
    float sum = 0.f;
#pragma unroll
    for (int n = 0; n < NE; n++) { g[n] = expf(g[n] - m); sum += g[n]; }
    float inv = 1.f / sum;
#pragma unroll
    for (int n = 0; n < NE; n++) g[n] *= inv;
    int i0 = 0;
#pragma unroll
    for (int n = 1; n < NE; n++) if (g[n] > g[i0]) i0 = n;
    int i1 = (i0 == 0) ? 1 : 0;
#pragma unroll
    for (int n = 0; n < NE; n++) if (n != i0 && g[n] > g[i1]) i1 = n;
    topk_idx[2 * t] = i0;     topk_idx[2 * t + 1] = i1;
    topk_val[2 * t] = g[i0];  topk_val[2 * t + 1] = g[i1];
  }
}

// counts + offsets + maxvio in one small kernel
__global__ __launch_bounds__(256) void k_finalize(const int* __restrict__ topk_idx,
    int* __restrict__ cnt, int* __restrict__ offs, int* __restrict__ cursor,
    float* __restrict__ maxvio) {
  __shared__ int lc[NE];
  if (threadIdx.x < NE) lc[threadIdx.x] = 0;
  __syncthreads();
#pragma unroll
  for (int i = 0; i < 16; i++) {
    int e = topk_idx[threadIdx.x * 16 + i];
    atomicAdd(&lc[e], 1);
  }
  __syncthreads();
  if (threadIdx.x == 0) {
    int o = 0, mx = 0;
#pragma unroll
    for (int n = 0; n < NE; n++) {
      int c = lc[n];
      cnt[n] = c; offs[n] = o; cursor[n] = 0;
      o += c; mx = max(mx, c);
    }
    maxvio[0] = ((float)mx - 512.f) / 512.f;
  }
}

__global__ __launch_bounds__(256) void k_place(const int* __restrict__ topk_idx,
    const int* __restrict__ offs, int* __restrict__ cursor,
    int* __restrict__ rowtok, int* __restrict__ pairpos) {
  int t = blockIdx.x * 256 + threadIdx.x;
  if (t >= T_TOK) return;
#pragma unroll
  for (int k = 0; k < 2; k++) {
    int e = topk_idx[2 * t + k];
    int pos = atomicAdd(&cursor[e], 1);
    rowtok[offs[e] + pos] = t;
    pairpos[2 * t + k] = offs[e] + pos;
  }
}

// ---------------- GEMMs: in-kernel W transpose+cast, reg-prefetch pipeline ----
#define BM 128
#define BN 128
#define BK 64

// C = gather(u)[M,K=1024] x W1[k][n]; epilogue relu(acc+b1) -> h bf16
__global__ __launch_bounds__(256, 2) void k_gemm1(const unsigned short* __restrict__ ub,
    const float* __restrict__ W1, const float* __restrict__ b1,
    const int* __restrict__ rowtok, const int* __restrict__ cnts, const int* __restrict__ offs,
    unsigned short* __restrict__ h) {
  int e = blockIdx.z;
  int cnt = cnts[e];
  int m0 = blockIdx.y * BM;
  if (m0 >= cnt) return;
  int off = offs[e];
  int n0 = blockIdx.x * BN;
  __shared__ __align__(16) unsigned char smem[32768];

  int tid = threadIdx.x;
  int lane = tid & 63;
  int wv = tid >> 6;
  int wm = (tid >> 7) & 1;
  int wn = (tid >> 6) & 1;
  int srow = tid >> 3;
  int cp = tid & 7;
  const float* w1e = W1 + (size_t)e * DIMS * HID;
  const unsigned short* gAp[4];
#pragma unroll
  for (int a = 0; a < 4; a++) {
    int r = a * 32 + srow;
    int c = cp ^ (r & 7);
    int pr = min(off + m0 + r, off + cnt - 1);
    int tok = rowtok[pr];
    gAp[a] = ub + (size_t)tok * DIMS + c * 8;
  }
  // B staging geometry (per-thread, fixed): j = wv*4+jj
  const float* gBp[4];
  int csw[4], nlv[4];
#pragma unroll
  for (int jj = 0; jj < 4; jj++) {
    int j = wv * 4 + jj;
    int kc = j & 7, nh = j >> 3;
    int nloc = nh * 64 + lane;
    nlv[jj] = nloc;
    csw[jj] = kc ^ (lane & 7);
    gBp[jj] = w1e + (size_t)(kc * 8) * HID + n0 + nloc;
  }
  int wboff = __builtin_amdgcn_readfirstlane(wv << 10);
  unsigned aWr = (unsigned)(wboff + lane * 16);
  f32x4 acc[4][4];
  f32x4 zz = {0.f, 0.f, 0.f, 0.f};
#pragma unroll
  for (int i = 0; i < 4; i++)
#pragma unroll
    for (int j = 0; j < 4; j++) acc[i][j] = zz;

  int lane15 = lane & 15, quad = lane >> 4, l7 = lane & 7;
  unsigned aRowOff = (unsigned)((wm * 64 + lane15) * 128);
  unsigned bRowOff = (unsigned)(16384 + (wn * 64 + lane15) * 128);

  // ---- prologue: stage tile k=0 ----
#pragma unroll
  for (int a = 0; a < 4; a++) g2l16(gAp[a], smem + a * 4096 + wboff);
  {
    float bp[32];
#pragma unroll
    for (int jj = 0; jj < 4; jj++) {
      const float* src = gBp[jj];
#pragma unroll
      for (int i = 0; i < 8; i++) bp[jj * 8 + i] = src[(size_t)i * HID];
    }
#pragma unroll
    for (int jj = 0; jj < 4; jj++) {
      bf16x8 pk;
#pragma unroll
      for (int i = 0; i < 8; i++) pk[i] = (__bf16)bp[jj * 8 + i];
      *(bf16x8*)(smem + 16384 + nlv[jj] * 128 + csw[jj] * 16) = pk;
    }
  }
  __syncthreads();

#pragma unroll 1
  for (int k0 = 0; k0 < DIMS; k0 += BK) {
    int kn = k0 + BK;
    uint4 apre[4];
    float bp[32];
    if (kn < DIMS) {
#pragma unroll
      for (int a = 0; a < 4; a++) apre[a] = *(const uint4*)(gAp[a] + kn);
#pragma unroll
      for (int jj = 0; jj < 4; jj++) {
        const float* src = gBp[jj] + (size_t)kn * HID;
#pragma unroll
        for (int i = 0; i < 8; i++) bp[jj * 8 + i] = src[(size_t)i * HID];
      }
    }
    // MFMA phase on tile k0 (LDS)
#pragma unroll
    for (int s = 0; s < 2; s++) {
      unsigned cpf = (unsigned)(((s * 4 + quad) ^ l7) * 16);
      bf16x8 af[4], bfr[4];
#pragma unroll
      for (int i = 0; i < 4; i++) af[i] = *(const bf16x8*)(smem + aRowOff + i * 2048 + cpf);
#pragma unroll
      for (int j = 0; j < 4; j++) bfr[j] = *(const bf16x8*)(smem + bRowOff + j * 2048 + cpf);
#pragma unroll
      for (int i = 0; i < 4; i++)
#pragma unroll
        for (int j = 0; j < 4; j++)
          acc[i][j] = __builtin_amdgcn_mfma_f32_16x16x32_bf16(af[i], bfr[j], acc[i][j], 0, 0, 0);
    }
    __syncthreads();
    if (kn < DIMS) {
#pragma unroll
      for (int a = 0; a < 4; a++) *(uint4*)(smem + a * 4096 + aWr) = apre[a];
#pragma unroll
      for (int jj = 0; jj < 4; jj++) {
        bf16x8 pk;
#pragma unroll
        for (int i = 0; i < 8; i++) pk[i] = (__bf16)bp[jj * 8 + i];
        *(bf16x8*)(smem + 16384 + nlv[jj] * 128 + csw[jj] * 16) = pk;
      }
      __syncthreads();
    }
  }
  float b1v[4];
#pragma unroll
  for (int j = 0; j < 4; j++) b1v[j] = b1[e * HID + n0 + wn * 64 + j * 16 + lane15];
#pragma unroll
  for (int i = 0; i < 4; i++) {
#pragma unroll
    for (int r = 0; r < 4; r++) {
      int mrow = m0 + wm * 64 + i * 16 + quad * 4 + r;
      if (mrow < cnt) {
        size_t hrow = (size_t)(off + mrow) * HID;
#pragma unroll
        for (int j = 0; j < 4; j++) {
          int col = n0 + wn * 64 + j * 16 + lane15;
          float v = fmaxf(acc[i][j][r] + b1v[j], 0.f);
          h[hrow + col] = f2bf(v);
        }
      }
    }
  }
}

// C = h[M,K] x W2[k][n] over K-split chunk; split 0 adds b2; bf16 partials
__global__ __launch_bounds__(256, 2) void k_gemm2(const unsigned short* __restrict__ hbuf,
    const float* __restrict__ W2, const float* __restrict__ b2,
    const int* __restrict__ cnts, const int* __restrict__ offs,
    unsigned short* __restrict__ pout, int KC) {
  int z = blockIdx.z;
  int e = z & 7;
  int sp = z >> 3;
  int cnt = cnts[e];
  int m0 = blockIdx.y * BM;
  if (m0 >= cnt) return;
  int off = offs[e];
  int n0 = blockIdx.x * BN;
  __shared__ __align__(16) unsigned char smem[32768];

  int tid = threadIdx.x;
  int lane = tid & 63;
  int wv = tid >> 6;
  int wm = (tid >> 7) & 1;
  int wn = (tid >> 6) & 1;
  int srow = tid >> 3;
  int cp = tid & 7;
  const float* w2e = W2 + (size_t)e * HID * DIMS;
  const unsigned short* gAp[4];
#pragma unroll
  for (int a = 0; a < 4; a++) {
    int r = a * 32 + srow;
    int c = cp ^ (r & 7);
    int pr = min(off + m0 + r, off + cnt - 1);
    gAp[a] = hbuf + (size_t)pr * HID + c * 8;
  }
  const float* gBp[4];
  int csw[4], nlv[4];
#pragma unroll
  for (int jj = 0; jj < 4; jj++) {
    int j = wv * 4 + jj;
    int kc = j & 7, nh = j >> 3;
    int nloc = nh * 64 + lane;
    nlv[jj] = nloc;
    csw[jj] = kc ^ (lane & 7);
    gBp[jj] = w2e + (size_t)(kc * 8) * DIMS + n0 + nloc;
  }
  int wboff = __builtin_amdgcn_readfirstlane(wv << 10);
  unsigned aWr = (unsigned)(wboff + lane * 16);
  f32x4 acc[4][4];
  f32x4 zz = {0.f, 0.f, 0.f, 0.f};
#pragma unroll
  for (int i = 0; i < 4; i++)
#pragma unroll
    for (int j = 0; j < 4; j++) acc[i][j] = zz;

  int lane15 = lane & 15, quad = lane >> 4, l7 = lane & 7;
  unsigned aRowOff = (unsigned)((wm * 64 + lane15) * 128);
  unsigned bRowOff = (unsigned)(16384 + (wn * 64 + lane15) * 128);

  int kbeg = sp * KC, kend = kbeg + KC;
  // ---- prologue: stage tile kbeg ----
#pragma unroll
  for (int a = 0; a < 4; a++) g2l16(gAp[a] + kbeg, smem + a * 4096 + wboff);
  {
    float bp[32];
#pragma unroll
    for (int jj = 0; jj < 4; jj++) {
      const float* src = gBp[jj] + (size_t)kbeg * DIMS;
#pragma unroll
      for (int i = 0; i < 8; i++) bp[jj * 8 + i] = src[(size_t)i * DIMS];
    }
#pragma unroll
    for (int jj = 0; jj < 4; jj++) {
      bf16x8 pk;
#pragma unroll
      for (int i = 0; i < 8; i++) pk[i] = (__bf16)bp[jj * 8 + i];
      *(bf16x8*)(smem + 16384 + nlv[jj] * 128 + csw[jj] * 16) = pk;
    }
  }
  __syncthreads();

#pragma unroll 1
  for (int k0 = kbeg; k0 < kend; k0 += BK) {
    int kn = k0 + BK;
    uint4 apre[4];
    float bp[32];
    if (kn < kend) {
#pragma unroll
      for (int a = 0; a < 4; a++) apre[a] = *(const uint4*)(gAp[a] + kn);
#pragma unroll
      for (int jj = 0; jj < 4; jj++) {
        const float* src = gBp[jj] + (size_t)kn * DIMS;
#pragma unroll
        for (int i = 0; i < 8; i++) bp[jj * 8 + i] = src[(size_t)i * DIMS];
      }
    }
#pragma unroll
    for (int s = 0; s < 2; s++) {
      unsigned cpf = (unsigned)(((s * 4 + quad) ^ l7) * 16);
      bf16x8 af[4], bfr[4];
#pragma unroll
      for (int i = 0; i < 4; i++) af[i] = *(const bf16x8*)(smem + aRowOff + i * 2048 + cpf);
#pragma unroll
      for (int j = 0; j < 4; j++) bfr[j] = *(const bf16x8*)(smem + bRowOff + j * 2048 + cpf);
#pragma unroll
      for (int i = 0; i < 4; i++)
#pragma unroll
        for (int j = 0; j < 4; j++)
          acc[i][j] = __builtin_amdgcn_mfma_f32_16x16x32_bf16(af[i], bfr[j], acc[i][j], 0, 0, 0);
    }
    __syncthreads();
    if (kn < kend) {
#pragma unroll
      for (int a = 0; a < 4; a++) *(uint4*)(smem + a * 4096 + aWr) = apre[a];
#pragma unroll
      for (int jj = 0; jj < 4; jj++) {
        bf16x8 pk;
#pragma unroll
        for (int i = 0; i < 8; i++) pk[i] = (__bf16)bp[jj * 8 + i];
        *(bf16x8*)(smem + 16384 + nlv[jj] * 128 + csw[jj] * 16) = pk;
      }
      __syncthreads();
    }
  }
  float b2v[4];
#pragma unroll
  for (int j = 0; j < 4; j++)
    b2v[j] = (sp == 0) ? b2[e * DIMS + n0 + wn * 64 + j * 16 + lane15] : 0.f;
  unsigned short* pme = pout + (size_t)sp * T_TOK * 2 * DIMS;
#pragma unroll
  for (int i = 0; i < 4; i++) {
#pragma unroll
    for (int r = 0; r < 4; r++) {
      int mrow = m0 + wm * 64 + i * 16 + quad * 4 + r;
      if (mrow < cnt) {
        size_t prow = (size_t)(off + mrow) * DIMS;
#pragma unroll
        for (int j = 0; j < 4; j++) {
          int col = n0 + wn * 64 + j * 16 + lane15;
          pme[prow + col] = f2bf(acc[i][j][r] + b2v[j]);
        }
      }
    }
  }
}

// ---------------- combine (bf16 partials) ----------------
__global__ __launch_bounds__(256) void k_combine(const unsigned short* __restrict__ pout,
    const int* __restrict__ pairpos, const float* __restrict__ tkv,
    float* __restrict__ out, int nsplit) {
  int t = blockIdx.x;
  int d = threadIdx.x * 4;
  int p0 = pairpos[2 * t], p1 = pairpos[2 * t + 1];
  float w0 = tkv[2 * t], w1 = tkv[2 * t + 1];
  float a0 = 0.f, a1 = 0.f, a2 = 0.f, a3 = 0.f;
  float c0 = 0.f, c1 = 0.f, c2 = 0.f, c3 = 0.f;
  const size_t SS = (size_t)T_TOK * 2 * DIMS;
  for (int s = 0; s < nsplit; s++) {
    ushort4 av = *(const ushort4*)(pout + s * SS + (size_t)p0 * DIMS + d);
    ushort4 bv = *(const ushort4*)(pout + s * SS + (size_t)p1 * DIMS + d);
    a0 += bf2f(av.x); a1 += bf2f(av.y); a2 += bf2f(av.z); a3 += bf2f(av.w);
    c0 += bf2f(bv.x); c1 += bf2f(bv.y); c2 += bf2f(bv.z); c3 += bf2f(bv.w);
  }
  float4 o;
  o.x = w0 * a0 + w1 * c0;
  o.y = w0 * a1 + w1 * c1;
  o.z = w0 * a2 + w1 * c2;
  o.w = w0 * a3 + w1 * c3;
  *(float4*)(out + (size_t)t * DIMS + d) = o;
}

extern "C" void kernel_launch(void* const* d_in, const int* in_sizes, int n_in,
                              void* d_out, int out_size, void* d_ws, size_t ws_size,
                              hipStream_t stream) {
  const float* u     = (const float*)d_in[0];
  const float* cent  = (const float*)d_in[1];
  const float* sbias = (const float*)d_in[2];
  const float* W1    = (const float*)d_in[3];
  const float* b1    = (const float*)d_in[4];
  const float* W2    = (const float*)d_in[5];
  const float* b2    = (const float*)d_in[6];
  float* out = (float*)d_out;

  char* ws = (char*)d_ws;
  unsigned short* ubuf = (unsigned short*)(ws);                 //  4194304 B
  unsigned short* hbuf = (unsigned short*)(ws + 4194304);       // 33554432 B
  const size_t POUT_OFF = 37748736ull;
  const size_t PSZ = (size_t)T_TOK * 2 * DIMS * 2;              // 8 MB per split (bf16)
  int nsplit = (ws_size >= POUT_OFF + 4 * PSZ + (1u << 20)) ? 4 : 1;
  unsigned short* poutb = (unsigned short*)(ws + POUT_OFF);
  char* r = ws + POUT_OFF + (size_t)nsplit * PSZ;
  int*   cnt      = (int*)(r);
  int*   offs     = (int*)(r + 64);
  int*   cursor   = (int*)(r + 128);
  int*   topk_idx = (int*)(r + 256);
  float* topk_val = (float*)(r + 256 + 16384);
  int*   rowtok   = (int*)(r + 256 + 32768);
  int*   pairpos  = (int*)(r + 256 + 49152);

  k_route<<<512, 256, 0, stream>>>(u, cent, sbias, topk_idx, topk_val, ubuf);
  k_finalize<<<1, 256, 0, stream>>>(topk_idx, cnt, offs, cursor, out + 2097152);
  k_place<<<8, 256, 0, stream>>>(topk_idx, offs, cursor, rowtok, pairpos);
  k_gemm1<<<dim3(32, 16, 8), 256, 0, stream>>>(ubuf, W1, b1, rowtok, cnt, offs, hbuf);
  k_gemm2<<<dim3(8, 16, 8 * nsplit), 256, 0, stream>>>(hbuf, W2, b2, cnt, offs,
                                                       poutb, HID / nsplit);
  k_combine<<<2048, 256, 0, stream>>>(poutb, pairpos, topk_val, out, nsplit);
}

// Round 7
// 422.543 us; speedup vs baseline: 1.3215x; 1.3215x over previous
//
#include <hip/hip_runtime.h>
#include <hip/hip_bf16.h>

#define T_TOK 2048
#define DIMS  1024
#define HID   4096
#define NE    8

typedef __bf16 bf16x8 __attribute__((ext_vector_type(8)));
typedef float  f32x4  __attribute__((ext_vector_type(4)));

__device__ __forceinline__ unsigned short f2bf(float f) {
  unsigned u = __float_as_uint(f);
  u += 0x7FFFu + ((u >> 16) & 1u);
  return (unsigned short)(u >> 16);
}
__device__ __forceinline__ float bf2f(unsigned short s) {
  return __uint_as_float(((unsigned)s) << 16);
}

__device__ __forceinline__ void g2l16(const void* g, void* l) {
  __builtin_amdgcn_global_load_lds((const __attribute__((address_space(1))) void*)g,
                                   (__attribute__((address_space(3))) void*)l,
                                   16, 0, 0);
}

// ---------------- routing (+ fused u->bf16 cast) ----------------
__global__ __launch_bounds__(256) void k_route(const float* __restrict__ u,
    const float* __restrict__ cent, const float* __restrict__ sbias,
    int* __restrict__ topk_idx, float* __restrict__ topk_val,
    unsigned short* __restrict__ ub) {
  int wave = threadIdx.x >> 6;
  int lane = threadIdx.x & 63;
  int t = blockIdx.x * 4 + wave;
  const float* ur = u + (size_t)t * DIMS;
  float p[NE];
#pragma unroll
  for (int n = 0; n < NE; n++) p[n] = 0.f;
#pragma unroll
  for (int ch = 0; ch < 4; ch++) {
    int d = ch * 256 + lane * 4;
    float4 uv = *(const float4*)(ur + d);
    ushort4 o4;
    o4.x = f2bf(uv.x); o4.y = f2bf(uv.y); o4.z = f2bf(uv.z); o4.w = f2bf(uv.w);
    *(ushort4*)(ub + (size_t)t * DIMS + d) = o4;
#pragma unroll
    for (int n = 0; n < NE; n++) {
      float4 cv = *(const float4*)(cent + n * DIMS + d);
      p[n] += uv.x * cv.x + uv.y * cv.y + uv.z * cv.z + uv.w * cv.w;
    }
  }
#pragma unroll
  for (int n = 0; n < NE; n++) {
#pragma unroll
    for (int o = 32; o > 0; o >>= 1) p[n] += __shfl_xor(p[n], o);
  }
  if (lane == 0) {
    float g[NE];
    float m = -1e30f;
#pragma unroll
    for (int n = 0; n < NE; n++) { g[n] = p[n] + sbias[n]; m = fmaxf(m, g[n]); }
    float sum = 0.f;
#pragma unroll
    for (int n = 0; n < NE; n++) { g[n] = expf(g[n] - m); sum += g[n]; }
    float inv = 1.f / sum;
#pragma unroll
    for (int n = 0; n < NE; n++) g[n] *= inv;
    int i0 = 0;
#pragma unroll
    for (int n = 1; n < NE; n++) if (g[n] > g[i0]) i0 = n;
    int i1 = (i0 == 0) ? 1 : 0;
#pragma unroll
    for (int n = 0; n < NE; n++) if (n != i0 && g[n] > g[i1]) i1 = n;
    topk_idx[2 * t] = i0;     topk_idx[2 * t + 1] = i1;
    topk_val[2 * t] = g[i0];  topk_val[2 * t + 1] = g[i1];
  }
}

// counts + offsets + maxvio + placement, one block
__global__ __launch_bounds__(256) void k_finalize(const int* __restrict__ topk_idx,
    int* __restrict__ cnt, int* __restrict__ offs, float* __restrict__ maxvio,
    int* __restrict__ rowtok, int* __restrict__ pairpos) {
  __shared__ int lc[NE], loff[NE], lcur[NE];
  int tid = threadIdx.x;
  if (tid < NE) lc[tid] = 0;
  __syncthreads();
#pragma unroll
  for (int i = 0; i < 16; i++) {
    int e = topk_idx[tid * 16 + i];
    atomicAdd(&lc[e], 1);
  }
  __syncthreads();
  if (tid == 0) {
    int o = 0, mx = 0;
#pragma unroll
    for (int n = 0; n < NE; n++) {
      int c = lc[n];
      cnt[n] = c; offs[n] = o; loff[n] = o; lcur[n] = o;
      o += c; mx = max(mx, c);
    }
    maxvio[0] = ((float)mx - 512.f) / 512.f;
  }
  __syncthreads();
#pragma unroll
  for (int i = 0; i < 8; i++) {
    int t = tid + i * 256;
#pragma unroll
    for (int k = 0; k < 2; k++) {
      int e = topk_idx[2 * t + k];
      int pos = atomicAdd(&lcur[e], 1);
      rowtok[pos] = t;
      pairpos[2 * t + k] = pos;
    }
  }
}

// ---------------- GEMMs (in-kernel W transpose+cast staging) ----------------
#define BM 128
#define BN 128
#define BK 64

// C = gather(u)[M,K=1024] x W1[k][n]; epilogue relu(acc+b1) -> h bf16
__global__ __launch_bounds__(256) void k_gemm1(const unsigned short* __restrict__ ub,
    const float* __restrict__ W1, const float* __restrict__ b1,
    const int* __restrict__ rowtok, const int* __restrict__ cnts, const int* __restrict__ offs,
    unsigned short* __restrict__ h) {
  int e = blockIdx.z;
  int cnt = cnts[e];
  int m0 = blockIdx.y * BM;
  if (m0 >= cnt) return;
  int off = offs[e];
  int n0 = blockIdx.x * BN;
  __shared__ __align__(16) unsigned char smem[32768];

  int tid = threadIdx.x;
  int lane = tid & 63;
  int wv = tid >> 6;
  int wm = (tid >> 7) & 1;
  int wn = (tid >> 6) & 1;
  int srow = tid >> 3;
  int cp = tid & 7;
  const float* w1e = W1 + (size_t)e * DIMS * HID;
  const unsigned short* gAp[4];
#pragma unroll
  for (int a = 0; a < 4; a++) {
    int r = a * 32 + srow;
    int c = cp ^ (r & 7);
    int pr = min(off + m0 + r, off + cnt - 1);
    int tok = rowtok[pr];
    gAp[a] = ub + (size_t)tok * DIMS + c * 8;
  }
  int wboff = __builtin_amdgcn_readfirstlane(wv << 10);
  f32x4 acc[4][4];
  f32x4 zz = {0.f, 0.f, 0.f, 0.f};
#pragma unroll
  for (int i = 0; i < 4; i++)
#pragma unroll
    for (int j = 0; j < 4; j++) acc[i][j] = zz;

  int lane15 = lane & 15, quad = lane >> 4, l7 = lane & 7;
  unsigned aRowOff = (unsigned)((wm * 64 + lane15) * 128);
  unsigned bRowOff = (unsigned)(16384 + (wn * 64 + lane15) * 128);

#pragma unroll 1
  for (int k0 = 0; k0 < DIMS; k0 += BK) {
#pragma unroll
    for (int a = 0; a < 4; a++) g2l16(gAp[a] + k0, smem + a * 4096 + wboff);
    // B staging: W1 fp32 [k][n] tile -> LDS [n][k] bf16, swizzled
#pragma unroll
    for (int jj = 0; jj < 4; jj++) {
      int j = wv * 4 + jj;
      int kc = j & 7, nh = j >> 3;
      int nloc = nh * 64 + lane;
      const float* src = w1e + (size_t)(k0 + kc * 8) * HID + n0 + nloc;
      float t0, t1, t2, t3, t4, t5, t6, t7;
      t0 = src[0];            t1 = src[(size_t)HID];
      t2 = src[(size_t)2 * HID]; t3 = src[(size_t)3 * HID];
      t4 = src[(size_t)4 * HID]; t5 = src[(size_t)5 * HID];
      t6 = src[(size_t)6 * HID]; t7 = src[(size_t)7 * HID];
      bf16x8 pk;
      pk[0] = (__bf16)t0; pk[1] = (__bf16)t1; pk[2] = (__bf16)t2; pk[3] = (__bf16)t3;
      pk[4] = (__bf16)t4; pk[5] = (__bf16)t5; pk[6] = (__bf16)t6; pk[7] = (__bf16)t7;
      int cs = kc ^ (lane & 7);
      *(bf16x8*)(smem + 16384 + nloc * 128 + cs * 16) = pk;
    }
    __syncthreads();
#pragma unroll
    for (int s = 0; s < 2; s++) {
      unsigned cpf = (unsigned)(((s * 4 + quad) ^ l7) * 16);
      bf16x8 af[4], bfr[4];
#pragma unroll
      for (int i = 0; i < 4; i++) af[i] = *(const bf16x8*)(smem + aRowOff + i * 2048 + cpf);
#pragma unroll
      for (int j = 0; j < 4; j++) bfr[j] = *(const bf16x8*)(smem + bRowOff + j * 2048 + cpf);
#pragma unroll
      for (int i = 0; i < 4; i++)
#pragma unroll
        for (int j = 0; j < 4; j++)
          acc[i][j] = __builtin_amdgcn_mfma_f32_16x16x32_bf16(af[i], bfr[j], acc[i][j], 0, 0, 0);
    }
    __syncthreads();
  }
  float b1v[4];
#pragma unroll
  for (int j = 0; j < 4; j++) b1v[j] = b1[e * HID + n0 + wn * 64 + j * 16 + lane15];
#pragma unroll
  for (int i = 0; i < 4; i++) {
#pragma unroll
    for (int r = 0; r < 4; r++) {
      int mrow = m0 + wm * 64 + i * 16 + quad * 4 + r;
      if (mrow < cnt) {
        size_t hrow = (size_t)(off + mrow) * HID;
#pragma unroll
        for (int j = 0; j < 4; j++) {
          int col = n0 + wn * 64 + j * 16 + lane15;
          float v = fmaxf(acc[i][j][r] + b1v[j], 0.f);
          h[hrow + col] = f2bf(v);
        }
      }
    }
  }
}

// C = h[M,K] x W2[k][n] over K-split chunk; split 0 adds b2; bf16 partials
__global__ __launch_bounds__(256) void k_gemm2(const unsigned short* __restrict__ hbuf,
    const float* __restrict__ W2, const float* __restrict__ b2,
    const int* __restrict__ cnts, const int* __restrict__ offs,
    unsigned short* __restrict__ pout, int KC) {
  int z = blockIdx.z;
  int e = z & 7;
  int sp = z >> 3;
  int cnt = cnts[e];
  int m0 = blockIdx.y * BM;
  if (m0 >= cnt) return;
  int off = offs[e];
  int n0 = blockIdx.x * BN;
  __shared__ __align__(16) unsigned char smem[32768];

  int tid = threadIdx.x;
  int lane = tid & 63;
  int wv = tid >> 6;
  int wm = (tid >> 7) & 1;
  int wn = (tid >> 6) & 1;
  int srow = tid >> 3;
  int cp = tid & 7;
  const float* w2e = W2 + (size_t)e * HID * DIMS;
  const unsigned short* gAp[4];
#pragma unroll
  for (int a = 0; a < 4; a++) {
    int r = a * 32 + srow;
    int c = cp ^ (r & 7);
    int pr = min(off + m0 + r, off + cnt - 1);
    gAp[a] = hbuf + (size_t)pr * HID + c * 8;
  }
  int wboff = __builtin_amdgcn_readfirstlane(wv << 10);
  f32x4 acc[4][4];
  f32x4 zz = {0.f, 0.f, 0.f, 0.f};
#pragma unroll
  for (int i = 0; i < 4; i++)
#pragma unroll
    for (int j = 0; j < 4; j++) acc[i][j] = zz;

  int lane15 = lane & 15, quad = lane >> 4, l7 = lane & 7;
  unsigned aRowOff = (unsigned)((wm * 64 + lane15) * 128);
  unsigned bRowOff = (unsigned)(16384 + (wn * 64 + lane15) * 128);

  int kbeg = sp * KC, kend = kbeg + KC;
#pragma unroll 1
  for (int k0 = kbeg; k0 < kend; k0 += BK) {
#pragma unroll
    for (int a = 0; a < 4; a++) g2l16(gAp[a] + k0, smem + a * 4096 + wboff);
#pragma unroll
    for (int jj = 0; jj < 4; jj++) {
      int j = wv * 4 + jj;
      int kc = j & 7, nh = j >> 3;
      int nloc = nh * 64 + lane;
      const float* src = w2e + (size_t)(k0 + kc * 8) * DIMS + n0 + nloc;
      float t0, t1, t2, t3, t4, t5, t6, t7;
      t0 = src[0];             t1 = src[(size_t)DIMS];
      t2 = src[(size_t)2 * DIMS]; t3 = src[(size_t)3 * DIMS];
      t4 = src[(size_t)4 * DIMS]; t5 = src[(size_t)5 * DIMS];
      t6 = src[(size_t)6 * DIMS]; t7 = src[(size_t)7 * DIMS];
      bf16x8 pk;
      pk[0] = (__bf16)t0; pk[1] = (__bf16)t1; pk[2] = (__bf16)t2; pk[3] = (__bf16)t3;
      pk[4] = (__bf16)t4; pk[5] = (__bf16)t5; pk[6] = (__bf16)t6; pk[7] = (__bf16)t7;
      int cs = kc ^ (lane & 7);
      *(bf16x8*)(smem + 16384 + nloc * 128 + cs * 16) = pk;
    }
    __syncthreads();
#pragma unroll
    for (int s = 0; s < 2; s++) {
      unsigned cpf = (unsigned)(((s * 4 + quad) ^ l7) * 16);
      bf16x8 af[4], bfr[4];
#pragma unroll
      for (int i = 0; i < 4; i++) af[i] = *(const bf16x8*)(smem + aRowOff + i * 2048 + cpf);
#pragma unroll
      for (int j = 0; j < 4; j++) bfr[j] = *(const bf16x8*)(smem + bRowOff + j * 2048 + cpf);
#pragma unroll
      for (int i = 0; i < 4; i++)
#pragma unroll
        for (int j = 0; j < 4; j++)
          acc[i][j] = __builtin_amdgcn_mfma_f32_16x16x32_bf16(af[i], bfr[j], acc[i][j], 0, 0, 0);
    }
    __syncthreads();
  }
  float b2v[4];
#pragma unroll
  for (int j = 0; j < 4; j++)
    b2v[j] = (sp == 0) ? b2[e * DIMS + n0 + wn * 64 + j * 16 + lane15] : 0.f;
  unsigned short* pme = pout + (size_t)sp * T_TOK * 2 * DIMS;
#pragma unroll
  for (int i = 0; i < 4; i++) {
#pragma unroll
    for (int r = 0; r < 4; r++) {
      int mrow = m0 + wm * 64 + i * 16 + quad * 4 + r;
      if (mrow < cnt) {
        size_t prow = (size_t)(off + mrow) * DIMS;
#pragma unroll
        for (int j = 0; j < 4; j++) {
          int col = n0 + wn * 64 + j * 16 + lane15;
          pme[prow + col] = f2bf(acc[i][j][r] + b2v[j]);
        }
      }
    }
  }
}

// ---------------- combine (bf16 partials) ----------------
__global__ __launch_bounds__(256) void k_combine(const unsigned short* __restrict__ pout,
    const int* __restrict__ pairpos, const float* __restrict__ tkv,
    float* __restrict__ out, int nsplit) {
  int t = blockIdx.x;
  int d = threadIdx.x * 4;
  int p0 = pairpos[2 * t], p1 = pairpos[2 * t + 1];
  float w0 = tkv[2 * t], w1 = tkv[2 * t + 1];
  float a0 = 0.f, a1 = 0.f, a2 = 0.f, a3 = 0.f;
  float c0 = 0.f, c1 = 0.f, c2 = 0.f, c3 = 0.f;
  const size_t SS = (size_t)T_TOK * 2 * DIMS;
  for (int s = 0; s < nsplit; s++) {
    ushort4 av = *(const ushort4*)(pout + s * SS + (size_t)p0 * DIMS + d);
    ushort4 bv = *(const ushort4*)(pout + s * SS + (size_t)p1 * DIMS + d);
    a0 += bf2f(av.x); a1 += bf2f(av.y); a2 += bf2f(av.z); a3 += bf2f(av.w);
    c0 += bf2f(bv.x); c1 += bf2f(bv.y); c2 += bf2f(bv.z); c3 += bf2f(bv.w);
  }
  float4 o;
  o.x = w0 * a0 + w1 * c0;
  o.y = w0 * a1 + w1 * c1;
  o.z = w0 * a2 + w1 * c2;
  o.w = w0 * a3 + w1 * c3;
  *(float4*)(out + (size_t)t * DIMS + d) = o;
}

extern "C" void kernel_launch(void* const* d_in, const int* in_sizes, int n_in,
                              void* d_out, int out_size, void* d_ws, size_t ws_size,
                              hipStream_t stream) {
  const float* u     = (const float*)d_in[0];
  const float* cent  = (const float*)d_in[1];
  const float* sbias = (const float*)d_in[2];
  const float* W1    = (const float*)d_in[3];
  const float* b1    = (const float*)d_in[4];
  const float* W2    = (const float*)d_in[5];
  const float* b2    = (const float*)d_in[6];
  float* out = (float*)d_out;

  char* ws = (char*)d_ws;
  unsigned short* ubuf = (unsigned short*)(ws);                 //  4194304 B
  unsigned short* hbuf = (unsigned short*)(ws + 4194304);       // 33554432 B
  const size_t POUT_OFF = 37748736ull;
  const size_t PSZ = (size_t)T_TOK * 2 * DIMS * 2;              // 8 MB per split (bf16)
  int nsplit = (ws_size >= POUT_OFF + 8 * PSZ + (1u << 20)) ? 8 : 1;
  unsigned short* poutb = (unsigned short*)(ws + POUT_OFF);
  char* r = ws + POUT_OFF + (size_t)nsplit * PSZ;
  int*   cnt      = (int*)(r);
  int*   offs     = (int*)(r + 64);
  int*   topk_idx = (int*)(r + 256);
  float* topk_val = (float*)(r + 256 + 16384);
  int*   rowtok   = (int*)(r + 256 + 32768);
  int*   pairpos  = (int*)(r + 256 + 49152);

  k_route<<<512, 256, 0, stream>>>(u, cent, sbias, topk_idx, topk_val, ubuf);
  k_finalize<<<1, 256, 0, stream>>>(topk_idx, cnt, offs, out + 2097152, rowtok, pairpos);
  k_gemm1<<<dim3(32, 16, 8), 256, 0, stream>>>(ubuf, W1, b1, rowtok, cnt, offs, hbuf);
  k_gemm2<<<dim3(8, 16, 8 * nsplit), 256, 0, stream>>>(hbuf, W2, b2, cnt, offs,
                                                       poutb, HID / nsplit);
  k_combine<<<2048, 256, 0, stream>>>(poutb, pairpos, topk_val, out, nsplit);
}

// Round 8
// 417.604 us; speedup vs baseline: 1.3371x; 1.0118x over previous
//
#include <hip/hip_runtime.h>
#include <hip/hip_bf16.h>

#define T_TOK 2048
#define DIMS  1024
#define HID   4096
#define NE    8

typedef __bf16 bf16x8 __attribute__((ext_vector_type(8)));
typedef float  f32x4  __attribute__((ext_vector_type(4)));

__device__ __forceinline__ unsigned short f2bf(float f) {
  unsigned u = __float_as_uint(f);
  u += 0x7FFFu + ((u >> 16) & 1u);
  return (unsigned short)(u >> 16);
}
__device__ __forceinline__ float bf2f(unsigned short s) {
  return __uint_as_float(((unsigned)s) << 16);
}

__device__ __forceinline__ void g2l16(const void* g, void* l) {
  __builtin_amdgcn_global_load_lds((const __attribute__((address_space(1))) void*)g,
                                   (__attribute__((address_space(3))) void*)l,
                                   16, 0, 0);
}

// ---------------- routing (+ fused u->bf16 cast) ----------------
__global__ __launch_bounds__(256) void k_route(const float* __restrict__ u,
    const float* __restrict__ cent, const float* __restrict__ sbias,
    int* __restrict__ topk_idx, float* __restrict__ topk_val,
    unsigned short* __restrict__ ub) {
  int wave = threadIdx.x >> 6;
  int lane = threadIdx.x & 63;
  int t = blockIdx.x * 4 + wave;
  const float* ur = u + (size_t)t * DIMS;
  float p[NE];
#pragma unroll
  for (int n = 0; n < NE; n++) p[n] = 0.f;
#pragma unroll
  for (int ch = 0; ch < 4; ch++) {
    int d = ch * 256 + lane * 4;
    float4 uv = *(const float4*)(ur + d);
    ushort4 o4;
    o4.x = f2bf(uv.x); o4.y = f2bf(uv.y); o4.z = f2bf(uv.z); o4.w = f2bf(uv.w);
    *(ushort4*)(ub + (size_t)t * DIMS + d) = o4;
#pragma unroll
    for (int n = 0; n < NE; n++) {
      float4 cv = *(const float4*)(cent + n * DIMS + d);
      p[n] += uv.x * cv.x + uv.y * cv.y + uv.z * cv.z + uv.w * cv.w;
    }
  }
#pragma unroll
  for (int n = 0; n < NE; n++) {
#pragma unroll
    for (int o = 32; o > 0; o >>= 1) p[n] += __shfl_xor(p[n], o);
  }
  if (lane == 0) {
    float g[NE];
    float m = -1e30f;
#pragma unroll
    for (int n = 0; n < NE; n++) { g[n] = p[n] + sbias[n]; m = fmaxf(m, g[n]); }
    float sum = 0.f;
#pragma unroll
    for (int n = 0; n < NE; n++) { g[n] = expf(g[n] - m); sum += g[n]; }
    float inv = 1.f / sum;
#pragma unroll
    for (int n = 0; n < NE; n++) g[n] *= inv;
    int i0 = 0;
#pragma unroll
    for (int n = 1; n < NE; n++) if (g[n] > g[i0]) i0 = n;
    int i1 = (i0 == 0) ? 1 : 0;
#pragma unroll
    for (int n = 0; n < NE; n++) if (n != i0 && g[n] > g[i1]) i1 = n;
    topk_idx[2 * t] = i0;     topk_idx[2 * t + 1] = i1;
    topk_val[2 * t] = g[i0];  topk_val[2 * t + 1] = g[i1];
  }
}

// counts + offsets + maxvio + placement, one block
__global__ __launch_bounds__(256) void k_finalize(const int* __restrict__ topk_idx,
    int* __restrict__ cnt, int* __restrict__ offs, float* __restrict__ maxvio,
    int* __restrict__ rowtok, int* __restrict__ pairpos) {
  __shared__ int lc[NE], lcur[NE];
  int tid = threadIdx.x;
  if (tid < NE) lc[tid] = 0;
  __syncthreads();
#pragma unroll
  for (int i = 0; i < 16; i++) {
    int e = topk_idx[tid * 16 + i];
    atomicAdd(&lc[e], 1);
  }
  __syncthreads();
  if (tid == 0) {
    int o = 0, mx = 0;
#pragma unroll
    for (int n = 0; n < NE; n++) {
      int c = lc[n];
      cnt[n] = c; offs[n] = o; lcur[n] = o;
      o += c; mx = max(mx, c);
    }
    maxvio[0] = ((float)mx - 512.f) / 512.f;
  }
  __syncthreads();
#pragma unroll
  for (int i = 0; i < 8; i++) {
    int t = tid + i * 256;
#pragma unroll
    for (int k = 0; k < 2; k++) {
      int e = topk_idx[2 * t + k];
      int pos = atomicAdd(&lcur[e], 1);
      rowtok[pos] = t;
      pairpos[2 * t + k] = pos;
    }
  }
}

// ---------------- GEMM1 (+ W2 transpose in idle blocks) ----------------
#define BM 128
#define BN 128
#define BK 64

// Compute blocks: C = gather(u)[M,K=1024] x W1[k][n]; relu(acc+b1) -> h bf16.
// Idle blocks (m0 >= cnt): cast+transpose one 128x128 tile of W2 fp32[k][n]
// -> w2t bf16 [e][n][k], consumed by k_gemm2 (stream-ordered).
__global__ __launch_bounds__(256) void k_gemm1(const unsigned short* __restrict__ ub,
    const float* __restrict__ W1, const float* __restrict__ b1,
    const int* __restrict__ rowtok, const int* __restrict__ cnts, const int* __restrict__ offs,
    unsigned short* __restrict__ h,
    const float* __restrict__ W2, unsigned short* __restrict__ w2t) {
  __shared__ __align__(16) unsigned char smem[32768];
  int tid = threadIdx.x;
  int e = blockIdx.z;
  int cnt = cnts[e];
  int m0 = blockIdx.y * BM;

  if (m0 >= cnt) {
    // ---- W2 transpose worker ----
    int live[NE];
#pragma unroll
    for (int z = 0; z < NE; z++) live[z] = min(16, (cnts[z] + BM - 1) >> 7);
    int rank = 0;
    for (int z = 0; z < e; z++) rank += (16 - live[z]) * 32;
    rank += ((int)blockIdx.y - live[e]) * 32 + (int)blockIdx.x;
    if (rank >= 2048) return;
    int te = rank >> 8, tt = rank & 255;
    int r0 = (tt & 31) * 128, c0 = (tt >> 5) * 128;   // r: HID(k) rows, c: DIMS(n) cols
    const float* Wsrc = W2 + (size_t)te * HID * DIMS;
    unsigned short* dst = w2t + (size_t)te * HID * DIMS;
    unsigned short* lds = (unsigned short*)smem;
    int rbase = tid >> 5;
    int c4l = (tid & 31) * 4;
#pragma unroll 4
    for (int it = 0; it < 16; it++) {
      int r = rbase + it * 8;
      float4 v = *(const float4*)(Wsrc + (size_t)(r0 + r) * DIMS + c0 + c4l);
      unsigned short b[4];
      b[0] = f2bf(v.x); b[1] = f2bf(v.y); b[2] = f2bf(v.z); b[3] = f2bf(v.w);
#pragma unroll
      for (int j = 0; j < 4; j++) {
        int c = c4l + j;
        int chunk = it ^ ((c >> 2) & 15);
        lds[c * 128 + chunk * 8 + rbase] = b[j];
      }
    }
    __syncthreads();
    int ck = tid & 15;
    int cb = tid >> 4;
#pragma unroll 4
    for (int it = 0; it < 8; it++) {
      int c = cb + it * 16;
      int chunk = ck ^ ((c >> 2) & 15);
      uint4 v = *(const uint4*)(&lds[c * 128 + chunk * 8]);
      *(uint4*)(dst + (size_t)(c0 + c) * HID + r0 + ck * 8) = v;
    }
    return;
  }

  // ---- GEMM compute path ----
  int off = offs[e];
  int n0 = blockIdx.x * BN;
  int lane = tid & 63;
  int wv = tid >> 6;
  int wm = (tid >> 7) & 1;
  int wn = (tid >> 6) & 1;
  int srow = tid >> 3;
  int cp = tid & 7;
  const float* w1e = W1 + (size_t)e * DIMS * HID;
  const unsigned short* gAp[4];
#pragma unroll
  for (int a = 0; a < 4; a++) {
    int r = a * 32 + srow;
    int c = cp ^ (r & 7);
    int pr = min(off + m0 + r, off + cnt - 1);
    int tok = rowtok[pr];
    gAp[a] = ub + (size_t)tok * DIMS + c * 8;
  }
  int wboff = __builtin_amdgcn_readfirstlane(wv << 10);
  f32x4 acc[4][4];
  f32x4 zz = {0.f, 0.f, 0.f, 0.f};
#pragma unroll
  for (int i = 0; i < 4; i++)
#pragma unroll
    for (int j = 0; j < 4; j++) acc[i][j] = zz;

  int lane15 = lane & 15, quad = lane >> 4, l7 = lane & 7;
  unsigned aRowOff = (unsigned)((wm * 64 + lane15) * 128);
  unsigned bRowOff = (unsigned)(16384 + (wn * 64 + lane15) * 128);

#pragma unroll 1
  for (int k0 = 0; k0 < DIMS; k0 += BK) {
#pragma unroll
    for (int a = 0; a < 4; a++) g2l16(gAp[a] + k0, smem + a * 4096 + wboff);
    // B staging: W1 fp32 [k][n] tile -> LDS [n][k] bf16, swizzled
#pragma unroll
    for (int jj = 0; jj < 4; jj++) {
      int j = wv * 4 + jj;
      int kc = j & 7, nh = j >> 3;
      int nloc = nh * 64 + lane;
      const float* src = w1e + (size_t)(k0 + kc * 8) * HID + n0 + nloc;
      float t0, t1, t2, t3, t4, t5, t6, t7;
      t0 = src[0];            t1 = src[(size_t)HID];
      t2 = src[(size_t)2 * HID]; t3 = src[(size_t)3 * HID];
      t4 = src[(size_t)4 * HID]; t5 = src[(size_t)5 * HID];
      t6 = src[(size_t)6 * HID]; t7 = src[(size_t)7 * HID];
      bf16x8 pk;
      pk[0] = (__bf16)t0; pk[1] = (__bf16)t1; pk[2] = (__bf16)t2; pk[3] = (__bf16)t3;
      pk[4] = (__bf16)t4; pk[5] = (__bf16)t5; pk[6] = (__bf16)t6; pk[7] = (__bf16)t7;
      int cs = kc ^ (lane & 7);
      *(bf16x8*)(smem + 16384 + nloc * 128 + cs * 16) = pk;
    }
    __syncthreads();
#pragma unroll
    for (int s = 0; s < 2; s++) {
      unsigned cpf = (unsigned)(((s * 4 + quad) ^ l7) * 16);
      bf16x8 af[4], bfr[4];
#pragma unroll
      for (int i = 0; i < 4; i++) af[i] = *(const bf16x8*)(smem + aRowOff + i * 2048 + cpf);
#pragma unroll
      for (int j = 0; j < 4; j++) bfr[j] = *(const bf16x8*)(smem + bRowOff + j * 2048 + cpf);
#pragma unroll
      for (int i = 0; i < 4; i++)
#pragma unroll
        for (int j = 0; j < 4; j++)
          acc[i][j] = __builtin_amdgcn_mfma_f32_16x16x32_bf16(af[i], bfr[j], acc[i][j], 0, 0, 0);
    }
    __syncthreads();
  }
  float b1v[4];
#pragma unroll
  for (int j = 0; j < 4; j++) b1v[j] = b1[e * HID + n0 + wn * 64 + j * 16 + lane15];
#pragma unroll
  for (int i = 0; i < 4; i++) {
#pragma unroll
    for (int r = 0; r < 4; r++) {
      int mrow = m0 + wm * 64 + i * 16 + quad * 4 + r;
      if (mrow < cnt) {
        size_t hrow = (size_t)(off + mrow) * HID;
#pragma unroll
        for (int j = 0; j < 4; j++) {
          int col = n0 + wn * 64 + j * 16 + lane15;
          float v = fmaxf(acc[i][j][r] + b1v[j], 0.f);
          h[hrow + col] = f2bf(v);
        }
      }
    }
  }
}

// ---------------- GEMM2: pure async staging from pre-transposed w2t ----------
// C = h[M,K] x w2t^T over K-split chunk; split 0 adds b2; bf16 partials
__global__ __launch_bounds__(256) void k_gemm2(const unsigned short* __restrict__ hbuf,
    const unsigned short* __restrict__ w2t, const float* __restrict__ b2,
    const int* __restrict__ cnts, const int* __restrict__ offs,
    unsigned short* __restrict__ pout, int KC) {
  int z = blockIdx.z;
  int e = z & 7;
  int sp = z >> 3;
  int cnt = cnts[e];
  int m0 = blockIdx.y * BM;
  if (m0 >= cnt) return;
  int off = offs[e];
  int n0 = blockIdx.x * BN;
  __shared__ __align__(16) unsigned char smem[32768];

  int tid = threadIdx.x;
  int lane = tid & 63;
  int wm = (tid >> 7) & 1;
  int wn = (tid >> 6) & 1;
  int srow = tid >> 3;
  int cp = tid & 7;
  const unsigned short* gA[4];
  const unsigned short* gB[4];
#pragma unroll
  for (int a = 0; a < 4; a++) {
    int r = a * 32 + srow;
    int c = cp ^ (r & 7);
    int pr = min(off + m0 + r, off + cnt - 1);
    gA[a] = hbuf + (size_t)pr * HID + c * 8;
    gB[a] = w2t + ((size_t)e * DIMS + (n0 + r)) * HID + c * 8;
  }
  int wboff = __builtin_amdgcn_readfirstlane((tid >> 6) << 10);
  f32x4 acc[4][4];
  f32x4 zz = {0.f, 0.f, 0.f, 0.f};
#pragma unroll
  for (int i = 0; i < 4; i++)
#pragma unroll
    for (int j = 0; j < 4; j++) acc[i][j] = zz;

  int lane15 = lane & 15, quad = lane >> 4, l7 = lane & 7;
  unsigned aRowOff = (unsigned)((wm * 64 + lane15) * 128);
  unsigned bRowOff = (unsigned)(16384 + (wn * 64 + lane15) * 128);

  int kbeg = sp * KC, kend = kbeg + KC;
#pragma unroll 1
  for (int k0 = kbeg; k0 < kend; k0 += BK) {
#pragma unroll
    for (int a = 0; a < 4; a++) g2l16(gA[a] + k0, smem + a * 4096 + wboff);
#pragma unroll
    for (int a = 0; a < 4; a++) g2l16(gB[a] + k0, smem + 16384 + a * 4096 + wboff);
    __syncthreads();
#pragma unroll
    for (int s = 0; s < 2; s++) {
      unsigned cpf = (unsigned)(((s * 4 + quad) ^ l7) * 16);
      bf16x8 af[4], bfr[4];
#pragma unroll
      for (int i = 0; i < 4; i++) af[i] = *(const bf16x8*)(smem + aRowOff + i * 2048 + cpf);
#pragma unroll
      for (int j = 0; j < 4; j++) bfr[j] = *(const bf16x8*)(smem + bRowOff + j * 2048 + cpf);
#pragma unroll
      for (int i = 0; i < 4; i++)
#pragma unroll
        for (int j = 0; j < 4; j++)
          acc[i][j] = __builtin_amdgcn_mfma_f32_16x16x32_bf16(af[i], bfr[j], acc[i][j], 0, 0, 0);
    }
    __syncthreads();
  }
  float b2v[4];
#pragma unroll
  for (int j = 0; j < 4; j++)
    b2v[j] = (sp == 0) ? b2[e * DIMS + n0 + wn * 64 + j * 16 + lane15] : 0.f;
  unsigned short* pme = pout + (size_t)sp * T_TOK * 2 * DIMS;
#pragma unroll
  for (int i = 0; i < 4; i++) {
#pragma unroll
    for (int r = 0; r < 4; r++) {
      int mrow = m0 + wm * 64 + i * 16 + quad * 4 + r;
      if (mrow < cnt) {
        size_t prow = (size_t)(off + mrow) * DIMS;
#pragma unroll
        for (int j = 0; j < 4; j++) {
          int col = n0 + wn * 64 + j * 16 + lane15;
          pme[prow + col] = f2bf(acc[i][j][r] + b2v[j]);
        }
      }
    }
  }
}

// ---------------- combine (bf16 partials) ----------------
__global__ __launch_bounds__(256) void k_combine(const unsigned short* __restrict__ pout,
    const int* __restrict__ pairpos, const float* __restrict__ tkv,
    float* __restrict__ out, int nsplit) {
  int t = blockIdx.x;
  int d = threadIdx.x * 4;
  int p0 = pairpos[2 * t], p1 = pairpos[2 * t + 1];
  float w0 = tkv[2 * t], w1 = tkv[2 * t + 1];
  float a0 = 0.f, a1 = 0.f, a2 = 0.f, a3 = 0.f;
  float c0 = 0.f, c1 = 0.f, c2 = 0.f, c3 = 0.f;
  const size_t SS = (size_t)T_TOK * 2 * DIMS;
  for (int s = 0; s < nsplit; s++) {
    ushort4 av = *(const ushort4*)(pout + s * SS + (size_t)p0 * DIMS + d);
    ushort4 bv = *(const ushort4*)(pout + s * SS + (size_t)p1 * DIMS + d);
    a0 += bf2f(av.x); a1 += bf2f(av.y); a2 += bf2f(av.z); a3 += bf2f(av.w);
    c0 += bf2f(bv.x); c1 += bf2f(bv.y); c2 += bf2f(bv.z); c3 += bf2f(bv.w);
  }
  float4 o;
  o.x = w0 * a0 + w1 * c0;
  o.y = w0 * a1 + w1 * c1;
  o.z = w0 * a2 + w1 * c2;
  o.w = w0 * a3 + w1 * c3;
  *(float4*)(out + (size_t)t * DIMS + d) = o;
}

extern "C" void kernel_launch(void* const* d_in, const int* in_sizes, int n_in,
                              void* d_out, int out_size, void* d_ws, size_t ws_size,
                              hipStream_t stream) {
  const float* u     = (const float*)d_in[0];
  const float* cent  = (const float*)d_in[1];
  const float* sbias = (const float*)d_in[2];
  const float* W1    = (const float*)d_in[3];
  const float* b1    = (const float*)d_in[4];
  const float* W2    = (const float*)d_in[5];
  const float* b2    = (const float*)d_in[6];
  float* out = (float*)d_out;

  char* ws = (char*)d_ws;
  unsigned short* ubuf = (unsigned short*)(ws);                 //  4194304 B
  unsigned short* hbuf = (unsigned short*)(ws + 4194304);       // 33554432 B
  unsigned short* w2t  = (unsigned short*)(ws + 37748736);      // 67108864 B
  const size_t POUT_OFF = 104857600ull;
  const size_t PSZ = (size_t)T_TOK * 2 * DIMS * 2;              // 8 MB per split (bf16)
  int nsplit = (ws_size >= POUT_OFF + 4 * PSZ + (1u << 20)) ? 4 : 1;
  unsigned short* poutb = (unsigned short*)(ws + POUT_OFF);
  char* r = ws + POUT_OFF + (size_t)nsplit * PSZ;
  int*   cnt      = (int*)(r);
  int*   offs     = (int*)(r + 64);
  int*   topk_idx = (int*)(r + 256);
  float* topk_val = (float*)(r + 256 + 16384);
  int*   rowtok   = (int*)(r + 256 + 32768);
  int*   pairpos  = (int*)(r + 256 + 49152);

  k_route<<<512, 256, 0, stream>>>(u, cent, sbias, topk_idx, topk_val, ubuf);
  k_finalize<<<1, 256, 0, stream>>>(topk_idx, cnt, offs, out + 2097152, rowtok, pairpos);
  k_gemm1<<<dim3(32, 16, 8), 256, 0, stream>>>(ubuf, W1, b1, rowtok, cnt, offs, hbuf,
                                               W2, w2t);
  k_gemm2<<<dim3(8, 16, 8 * nsplit), 256, 0, stream>>>(hbuf, w2t, b2, cnt, offs,
                                                       poutb, HID / nsplit);
  k_combine<<<2048, 256, 0, stream>>>(poutb, pairpos, topk_val, out, nsplit);
}